// Round 4
// baseline (1156.805 us; speedup 1.0000x reference)
//
#include <hip/hip_runtime.h>
#include <hip/hip_bf16.h>

#define DD 512
#define VV 54
#define NLEAF 60000
#define NINT 59881   // 119881 - 60000 internal nodes

typedef __attribute__((ext_vector_type(8))) short bf16x8;
typedef __attribute__((ext_vector_type(4))) float f32x4;

// ---------- bf16 helpers ----------
__device__ __forceinline__ float bflo(unsigned int u) {
    union { unsigned int i; float f; } v; v.i = u << 16; return v.f;
}
__device__ __forceinline__ float bfhi(unsigned int u) {
    union { unsigned int i; float f; } v; v.i = u & 0xffff0000u; return v.f;
}
__device__ __forceinline__ float bfu2f(unsigned short u) {
    union { unsigned int i; float f; } v; v.i = ((unsigned int)u) << 16; return v.f;
}
__device__ __forceinline__ unsigned short f2bfu(float f) {
    union { unsigned int i; float f; } v; v.f = f;
    unsigned int x = v.i;
    unsigned int r = (x + 0x7FFFu + ((x >> 16) & 1u)) >> 16;  // RN-even
    return (unsigned short)r;
}
__device__ __forceinline__ unsigned int pack2(float lo, float hi) {
    return (unsigned int)f2bfu(lo) | ((unsigned int)f2bfu(hi) << 16);
}
__device__ __forceinline__ float b2f(__hip_bfloat16 x) { return __bfloat162float(x); }
__device__ __forceinline__ float sigm(float x) { return 1.f / (1.f + __expf(-x)); }

// ---------- edge-index dtype self-detection ----------
__global__ void detect_idx64(const int* __restrict__ ec, int* __restrict__ flag) {
    __shared__ int nz;
    if (threadIdx.x == 0) nz = 0;
    __syncthreads();
    if (ec[2 * threadIdx.x + 1] != 0) atomicAdd(&nz, 1);
    __syncthreads();
    if (threadIdx.x == 0) flag[0] = (nz == 0) ? 1 : 0;
}

// ---------- one-time prep ----------
__global__ void prep_tables(const float* __restrict__ W_if, const float* __restrict__ b_f,
                            const float* __restrict__ W_i, const float* __restrict__ b_i,
                            const float* __restrict__ W_o, const float* __restrict__ b_o,
                            const float* __restrict__ W_u, const float* __restrict__ b_u,
                            float* __restrict__ wifc, float* __restrict__ tbi,
                            float* __restrict__ tbo, float* __restrict__ tbu,
                            __hip_bfloat16* __restrict__ hleaf, __hip_bfloat16* __restrict__ cleaf) {
    int t = blockIdx.x;  // 0..53
    for (int d = threadIdx.x; d < DD; d += blockDim.x) {
        wifc[t * DD + d] = W_if[d * VV + t] + b_f[d];
        float vi = W_i[d * (VV + DD) + t] + b_i[d];
        float vo = W_o[d * (VV + DD) + t] + b_o[d];
        float vu = W_u[d * (VV + DD) + t] + b_u[d];
        tbi[t * DD + d] = vi; tbo[t * DD + d] = vo; tbu[t * DD + d] = vu;
        float gi = sigm(vi), go = sigm(vo), gu = tanhf(vu);
        float c = gi * gu;
        float h = go * tanhf(c);
        hleaf[t * DD + d] = __float2bfloat16(h);
        cleaf[t * DD + d] = __float2bfloat16(c);
    }
}

__global__ void prep_whf_bf(const float* __restrict__ W_hf, __hip_bfloat16* __restrict__ Whf_bf) {
    int idx = blockIdx.x * 256 + threadIdx.x;  // 512*512
    Whf_bf[idx] = __float2bfloat16(W_hf[idx]);
}

__global__ void prep_wg_bf(const float* __restrict__ W_i, const float* __restrict__ W_o,
                           const float* __restrict__ W_u, __hip_bfloat16* __restrict__ Wg_bf) {
    int idx = blockIdx.x * 256 + threadIdx.x;  // 3*512*512
    int m = idx >> 18;
    int rem = idx & (DD * DD - 1);
    int d = rem >> 9, k = rem & 511;
    const float* W = (m == 0) ? W_i : ((m == 1) ? W_o : W_u);
    Wg_bf[idx] = __float2bfloat16(W[d * (VV + DD) + VV + k]);
}

// Fh54[t][d] = hleaf[t] . W_hf[d][:]   (m=0)
// Gh[m-1][t][d] = hleaf[t] . W_m[d][VV:]  (m=1,2,3 -> i,o,u)
__global__ void prep_typerows(const __hip_bfloat16* __restrict__ hleaf,
                              const float* __restrict__ W_hf, const float* __restrict__ W_i,
                              const float* __restrict__ W_o, const float* __restrict__ W_u,
                              float* __restrict__ Fh54, float* __restrict__ Gh) {
    __shared__ float hsh[DD];
    int t = blockIdx.x, m = blockIdx.y;
    for (int k = threadIdx.x; k < DD; k += 256) hsh[k] = b2f(hleaf[t * DD + k]);
    __syncthreads();
    const float* W; int stride, offc;
    if (m == 0) { W = W_hf; stride = DD; offc = 0; }
    else { W = (m == 1) ? W_i : ((m == 2) ? W_o : W_u); stride = VV + DD; offc = VV; }
    float* dst = (m == 0) ? (Fh54 + (size_t)t * DD) : (Gh + ((size_t)(m - 1) * VV + t) * DD);
    for (int d = threadIdx.x; d < DD; d += 256) {
        const float* wr = W + (size_t)d * stride + offc;
        float s = 0.f;
#pragma unroll 8
        for (int k = 0; k < DD; k++) s += hsh[k] * wr[k];
        dst[d] = s;
    }
}

// Tfc[tc][tp][d] = sigm(Fh54[tc][d] + wifc[tp][d]) * cleaf[tc][d]  (bf16)
__global__ void prep_tfc(const float* __restrict__ Fh54, const float* __restrict__ wifc,
                         const __hip_bfloat16* __restrict__ cleaf,
                         __hip_bfloat16* __restrict__ Tfc) {
    int pair = blockIdx.x;           // tc*54+tp, 2916 blocks
    int tc = pair / VV, tp = pair % VV;
    for (int d = threadIdx.x; d < DD; d += 256)
        Tfc[(size_t)pair * DD + d] = __float2bfloat16(
            sigm(Fh54[(size_t)tc * DD + d] + wifc[(size_t)tp * DD + d]) * b2f(cleaf[(size_t)tc * DD + d]));
}

// ---------- level-1 fused kernel (all children are leaves -> pure table lookups) ----------
__global__ __launch_bounds__(256) void level1_kernel(
    const int* __restrict__ nt, const int* __restrict__ ecb,
    const float* __restrict__ Gh, const float* __restrict__ tbi,
    const float* __restrict__ tbo, const float* __restrict__ tbu,
    const __hip_bfloat16* __restrict__ Tfc,
    __hip_bfloat16* __restrict__ Hrow, __hip_bfloat16* __restrict__ Crow,
    const int* __restrict__ idx64, int n) {
    int idx = blockIdx.x * 256 + threadIdx.x;
    int p = idx >> 6;
    if (p >= n) return;
    const int mode = idx64[0];
    int d0 = (idx & 63) << 3;
    int ta = nt[ecb[(2 * p) << mode]];
    int tb = nt[ecb[(2 * p + 1) << mode]];
    int tp = nt[NLEAF + p];
    const ushort4* fa = (const ushort4*)(Tfc + ((size_t)ta * VV + tp) * DD + d0);
    const ushort4* fb = (const ushort4*)(Tfc + ((size_t)tb * VV + tp) * DD + d0);
    ushort4 fa0 = fa[0], fa1 = fa[1], fb0 = fb[0], fb1 = fb[1];
    float cr[8] = {bfu2f(fa0.x) + bfu2f(fb0.x), bfu2f(fa0.y) + bfu2f(fb0.y),
                   bfu2f(fa0.z) + bfu2f(fb0.z), bfu2f(fa0.w) + bfu2f(fb0.w),
                   bfu2f(fa1.x) + bfu2f(fb1.x), bfu2f(fa1.y) + bfu2f(fb1.y),
                   bfu2f(fa1.z) + bfu2f(fb1.z), bfu2f(fa1.w) + bfu2f(fb1.w)};
    const float* gia = Gh + ((size_t)0 * VV + ta) * DD + d0;
    const float* gib = Gh + ((size_t)0 * VV + tb) * DD + d0;
    const float* goa = Gh + ((size_t)1 * VV + ta) * DD + d0;
    const float* gob = Gh + ((size_t)1 * VV + tb) * DD + d0;
    const float* gua = Gh + ((size_t)2 * VV + ta) * DD + d0;
    const float* gub = Gh + ((size_t)2 * VV + tb) * DD + d0;
    const float* ti = tbi + (size_t)tp * DD + d0;
    const float* to = tbo + (size_t)tp * DD + d0;
    const float* tu = tbu + (size_t)tp * DD + d0;
    float hv[8], cv[8];
#pragma unroll
    for (int j = 0; j < 8; j++) {
        float gi = sigm(gia[j] + gib[j] + ti[j]);
        float go = sigm(goa[j] + gob[j] + to[j]);
        float gu = tanhf(gua[j] + gub[j] + tu[j]);
        float c = gi * gu + cr[j];
        cv[j] = c;
        hv[j] = go * tanhf(c);
    }
    uint4 hp, cp;
    hp.x = pack2(hv[0], hv[1]); hp.y = pack2(hv[2], hv[3]);
    hp.z = pack2(hv[4], hv[5]); hp.w = pack2(hv[6], hv[7]);
    cp.x = pack2(cv[0], cv[1]); cp.y = pack2(cv[2], cv[3]);
    cp.z = pack2(cv[4], cv[5]); cp.w = pack2(cv[6], cv[7]);
    *(uint4*)(Hrow + (size_t)p * DD + d0) = hp;
    *(uint4*)(Crow + (size_t)p * DD + d0) = cp;
}

// ---------- gather helpers (leaves are virtual: table rows) ----------
__device__ __forceinline__ const __hip_bfloat16* h_row(int ci,
        const __hip_bfloat16* __restrict__ Hint, const __hip_bfloat16* __restrict__ hleaf,
        const int* __restrict__ nt) {
    return (ci < NLEAF) ? (hleaf + (size_t)nt[ci] * DD)
                        : (Hint + (size_t)(ci - NLEAF) * DD);
}
__device__ __forceinline__ const __hip_bfloat16* c_row(int ci,
        const __hip_bfloat16* __restrict__ Cint, const __hip_bfloat16* __restrict__ cleaf,
        const int* __restrict__ nt) {
    return (ci < NLEAF) ? (cleaf + (size_t)nt[ci] * DD)
                        : (Cint + (size_t)(ci - NLEAF) * DD);
}

// ============ GEMM F (MFMA): rows = edges, f-gate + in-lane pair-reduce -> crem ============
// tile 128(M) x 128(N), BK=32, 4 waves each 64x64. Fragment-major LDS (conflict-free).
__global__ __launch_bounds__(256) void gemm_f_mfma(
    const __hip_bfloat16* __restrict__ Hint, const __hip_bfloat16* __restrict__ Cint,
    const __hip_bfloat16* __restrict__ hleaf, const __hip_bfloat16* __restrict__ cleaf,
    const int* __restrict__ nt, const __hip_bfloat16* __restrict__ Whf_bf,
    const int* __restrict__ ecb, int eoff, const int* __restrict__ ntl,
    const float* __restrict__ wifc, __hip_bfloat16* __restrict__ crem,
    const int* __restrict__ idx64, int n) {
    __shared__ char lds[32768];  // 2 bufs x (A 8KB + B 8KB)
    const int M = 2 * n;
    const int mode = idx64[0];
    const int t = threadIdx.x;
    const int lane = t & 63, w = t >> 6, wr = w >> 1, wc = w & 1;
    const int row0 = blockIdx.x * 128, col0 = blockIdx.y * 128;

    const int srow = t & 127;
    const int sc = t >> 7;
    const __hip_bfloat16* aptr = nullptr;
    {
        int e = row0 + srow;
        if (e < M) {
            int ci = ecb[(eoff + e) << mode];
            aptr = h_row(ci, Hint, hleaf, nt);
        }
    }
    const __hip_bfloat16* bptr = Whf_bf + (size_t)(col0 + srow) * DD;
    const int wb = (srow >> 4) * 1024 + (srow & 15) * 16;

    f32x4 acc[4][4];
#pragma unroll
    for (int i = 0; i < 4; i++)
#pragma unroll
        for (int j = 0; j < 4; j++) acc[i][j] = {0.f, 0.f, 0.f, 0.f};

    uint4 ra0 = {0, 0, 0, 0}, ra1 = {0, 0, 0, 0}, rb0, rb1;
    if (aptr) { ra0 = *(const uint4*)(aptr + sc * 8); ra1 = *(const uint4*)(aptr + (sc + 2) * 8); }
    rb0 = *(const uint4*)(bptr + sc * 8);
    rb1 = *(const uint4*)(bptr + (sc + 2) * 8);

#pragma unroll 1
    for (int kt = 0; kt < 16; ++kt) {
        char* buf = lds + (kt & 1) * 16384;
        *(uint4*)(buf + wb + sc * 256) = ra0;
        *(uint4*)(buf + wb + (sc + 2) * 256) = ra1;
        *(uint4*)(buf + 8192 + wb + sc * 256) = rb0;
        *(uint4*)(buf + 8192 + wb + (sc + 2) * 256) = rb1;
        __syncthreads();
        if (kt < 15) {
            int ko = (kt + 1) * 32;
            if (aptr) {
                ra0 = *(const uint4*)(aptr + ko + sc * 8);
                ra1 = *(const uint4*)(aptr + ko + (sc + 2) * 8);
            }
            rb0 = *(const uint4*)(bptr + ko + sc * 8);
            rb1 = *(const uint4*)(bptr + ko + (sc + 2) * 8);
        }
        bf16x8 af[4], bfr[4];
#pragma unroll
        for (int i = 0; i < 4; i++)
            af[i] = *(const bf16x8*)(buf + (wr * 4 + i) * 1024 + lane * 16);
#pragma unroll
        for (int j = 0; j < 4; j++)
            bfr[j] = *(const bf16x8*)(buf + 8192 + (wc * 4 + j) * 1024 + lane * 16);
#pragma unroll
        for (int i = 0; i < 4; i++)
#pragma unroll
            for (int j = 0; j < 4; j++)
                acc[i][j] = __builtin_amdgcn_mfma_f32_16x16x32_bf16(af[i], bfr[j], acc[i][j], 0, 0, 0);
    }

    const int colb = col0 + wc * 64;
#pragma unroll
    for (int i = 0; i < 4; i++) {
        int er0 = row0 + wr * 64 + i * 16 + ((lane >> 4) << 2);
        if (er0 >= M) continue;
        bool hi = (er0 + 2) < M;
        int p0 = er0 >> 1;
        int t0 = ntl[p0];
        int t1 = hi ? ntl[p0 + 1] : 0;
        int ci0 = ecb[(eoff + er0) << mode];
        int ci1 = ecb[(eoff + er0 + 1) << mode];
        int ci2 = hi ? ecb[(eoff + er0 + 2) << mode] : ci0;
        int ci3 = hi ? ecb[(eoff + er0 + 3) << mode] : ci0;
        const __hip_bfloat16* cp0 = c_row(ci0, Cint, cleaf, nt);
        const __hip_bfloat16* cp1 = c_row(ci1, Cint, cleaf, nt);
        const __hip_bfloat16* cp2 = c_row(ci2, Cint, cleaf, nt);
        const __hip_bfloat16* cp3 = c_row(ci3, Cint, cleaf, nt);
        const float* wfa = wifc + (size_t)t0 * DD;
        const float* wfb = wifc + (size_t)t1 * DD;
#pragma unroll
        for (int j = 0; j < 4; j++) {
            int col = colb + j * 16 + (lane & 15);
            float wa = wfa[col], wbv = wfb[col];
            float s0 = sigm(acc[i][j].x + wa) * b2f(cp0[col])
                     + sigm(acc[i][j].y + wa) * b2f(cp1[col]);
            crem[(size_t)p0 * DD + col] = __float2bfloat16(s0);
            if (hi) {
                float s1 = sigm(acc[i][j].z + wbv) * b2f(cp2[col])
                         + sigm(acc[i][j].w + wbv) * b2f(cp3[col]);
                crem[(size_t)(p0 + 1) * DD + col] = __float2bfloat16(s1);
            }
        }
    }
}

// ============ GEMM G (MFMA): 512 threads, tile 128(M) x 128(N) x 3 gates, BK=32 ============
// 8 waves each 32x64x3. LDS 2 x (A 8KB + B 24KB) = 64KB -> 2 blocks/CU, 16 waves/CU.
__global__ __launch_bounds__(512) void gemm_g_mfma(
    const __hip_bfloat16* __restrict__ Hint, const __hip_bfloat16* __restrict__ hleaf,
    const int* __restrict__ nt, const __hip_bfloat16* __restrict__ Wg_bf,
    const int* __restrict__ ecb, int eoff, const int* __restrict__ ntl,
    const float* __restrict__ tbi, const float* __restrict__ tbo,
    const float* __restrict__ tbu, const __hip_bfloat16* __restrict__ crem,
    __hip_bfloat16* __restrict__ Hrow, __hip_bfloat16* __restrict__ Crow,
    float* __restrict__ outF, const int* __restrict__ idx64, int n) {
    __shared__ char lds[65536];
    const int mode = idx64[0];
    const int t = threadIdx.x;
    const int lane = t & 63, w = t >> 6;
    const int wr = w >> 1, wc = w & 1;             // wr 0..3 (32-row), wc 0..1 (64-col)
    const int row0 = blockIdx.x * 128, col0 = blockIdx.y * 128;

    // A staging: 128 rows x 32k; thread -> (row = t&127, chunk = t>>7)
    const int arow = t & 127, achk = t >> 7;
    const __hip_bfloat16 *pa = nullptr, *pb = nullptr;
    {
        int p = row0 + arow;
        if (p < n) {
            int c0 = ecb[(eoff + 2 * p) << mode];
            int c1 = ecb[(eoff + 2 * p + 1) << mode];
            pa = h_row(c0, Hint, hleaf, nt);
            pb = h_row(c1, Hint, hleaf, nt);
        }
    }
    const int wrA = (arow >> 4) * 1024 + (arow & 15) * 16 + achk * 256;
    // B staging: thread -> (col = t&127, chunk = t>>7) x 3 gates
    const int bcol = t & 127, bcw = t >> 7;
    const __hip_bfloat16* bbase = Wg_bf + (size_t)(col0 + bcol) * DD;
    const int wrB = 8192 + (bcol >> 4) * 1024 + (bcol & 15) * 16 + bcw * 256;

    f32x4 acc[3][2][4];
#pragma unroll
    for (int m = 0; m < 3; m++)
#pragma unroll
        for (int i = 0; i < 2; i++)
#pragma unroll
            for (int j = 0; j < 4; j++) acc[m][i][j] = {0.f, 0.f, 0.f, 0.f};

    uint4 rax = {0, 0, 0, 0}, ray = {0, 0, 0, 0};
    uint4 rb[3];
    if (pa) { rax = *(const uint4*)(pa + achk * 8); ray = *(const uint4*)(pb + achk * 8); }
#pragma unroll
    for (int m = 0; m < 3; m++)
        rb[m] = *(const uint4*)(bbase + (size_t)m * DD * DD + bcw * 8);

#pragma unroll 1
    for (int kt = 0; kt < 16; ++kt) {
        char* buf = lds + (kt & 1) * 32768;
        uint4 av;
        av.x = pack2(bflo(rax.x) + bflo(ray.x), bfhi(rax.x) + bfhi(ray.x));
        av.y = pack2(bflo(rax.y) + bflo(ray.y), bfhi(rax.y) + bfhi(ray.y));
        av.z = pack2(bflo(rax.z) + bflo(ray.z), bfhi(rax.z) + bfhi(ray.z));
        av.w = pack2(bflo(rax.w) + bflo(ray.w), bfhi(rax.w) + bfhi(ray.w));
        *(uint4*)(buf + wrA) = av;
#pragma unroll
        for (int m = 0; m < 3; m++)
            *(uint4*)(buf + wrB + m * 8192) = rb[m];
        __syncthreads();
        if (kt < 15) {
            int ko = (kt + 1) * 32;
            if (pa) { rax = *(const uint4*)(pa + ko + achk * 8); ray = *(const uint4*)(pb + ko + achk * 8); }
#pragma unroll
            for (int m = 0; m < 3; m++)
                rb[m] = *(const uint4*)(bbase + (size_t)m * DD * DD + ko + bcw * 8);
        }
        bf16x8 af[2], bff[3][4];
#pragma unroll
        for (int i = 0; i < 2; i++)
            af[i] = *(const bf16x8*)(buf + (wr * 2 + i) * 1024 + lane * 16);
#pragma unroll
        for (int m = 0; m < 3; m++)
#pragma unroll
            for (int j = 0; j < 4; j++)
                bff[m][j] = *(const bf16x8*)(buf + 8192 + m * 8192 + (wc * 4 + j) * 1024 + lane * 16);
#pragma unroll
        for (int m = 0; m < 3; m++)
#pragma unroll
            for (int i = 0; i < 2; i++)
#pragma unroll
                for (int j = 0; j < 4; j++)
                    acc[m][i][j] = __builtin_amdgcn_mfma_f32_16x16x32_bf16(af[i], bff[m][j], acc[m][i][j], 0, 0, 0);
    }

#pragma unroll
    for (int i = 0; i < 2; i++) {
        int r0 = row0 + wr * 32 + i * 16 + ((lane >> 4) << 2);
        int tt[4];
#pragma unroll
        for (int r = 0; r < 4; r++) tt[r] = (r0 + r < n) ? ntl[r0 + r] : 0;
#pragma unroll
        for (int j = 0; j < 4; j++) {
            int col = col0 + wc * 64 + j * 16 + (lane & 15);
#pragma unroll
            for (int r = 0; r < 4; r++) {
                int row = r0 + r;
                if (row >= n) continue;
                const float* pbi = tbi + (size_t)tt[r] * DD;
                const float* pbo = tbo + (size_t)tt[r] * DD;
                const float* pbu = tbu + (size_t)tt[r] * DD;
                float gi = sigm(acc[0][i][j][r] + pbi[col]);
                float go = sigm(acc[1][i][j][r] + pbo[col]);
                float gu = tanhf(acc[2][i][j][r] + pbu[col]);
                float c = gi * gu + b2f(crem[(size_t)row * DD + col]);
                float h = go * tanhf(c);
                Hrow[(size_t)row * DD + col] = __float2bfloat16(h);
                Crow[(size_t)row * DD + col] = __float2bfloat16(c);
                if (outF) outF[(size_t)row * DD + col] = h;
            }
        }
    }
}

extern "C" void kernel_launch(void* const* d_in, const int* in_sizes, int n_in,
                              void* d_out, int out_size, void* d_ws, size_t ws_size,
                              hipStream_t stream) {
    const int* node_types = (const int*)d_in[0];
    const int* edge_child = (const int*)d_in[2];
    const float* W_if = (const float*)d_in[6];
    const float* W_hf = (const float*)d_in[7];
    const float* b_f = (const float*)d_in[8];
    const float* W_i = (const float*)d_in[9];
    const float* b_i = (const float*)d_in[10];
    const float* W_o = (const float*)d_in[11];
    const float* b_o = (const float*)d_in[12];
    const float* W_u = (const float*)d_in[13];
    const float* b_u = (const float*)d_in[14];
    float* out = (float*)d_out;

    static const int ls[11] = {0, 60000, 90000, 105000, 112500, 116250,
                               118125, 119062, 119530, 119764, 119881};
    static const int es[11] = {0, 0, 60000, 90000, 105000, 112500,
                               116250, 118124, 119060, 119528, 119762};

    char* ws = (char*)d_ws;
    size_t off = 0;
    auto alloc = [&](size_t bytes) -> void* {
        void* p = ws + off;
        off += (bytes + 255) & ~(size_t)255;
        return p;
    };
    int* flag = (int*)alloc(256);
    __hip_bfloat16* Hint = (__hip_bfloat16*)alloc((size_t)NINT * DD * 2);
    __hip_bfloat16* Cint = (__hip_bfloat16*)alloc((size_t)NINT * DD * 2);
    __hip_bfloat16* crem = (__hip_bfloat16*)alloc((size_t)15000 * DD * 2);
    __hip_bfloat16* Whf_bf = (__hip_bfloat16*)alloc((size_t)DD * DD * 2);
    __hip_bfloat16* Wg_bf = (__hip_bfloat16*)alloc((size_t)3 * DD * DD * 2);
    float* wifc = (float*)alloc((size_t)VV * DD * 4);
    float* tbi = (float*)alloc((size_t)VV * DD * 4);
    float* tbo = (float*)alloc((size_t)VV * DD * 4);
    float* tbu = (float*)alloc((size_t)VV * DD * 4);
    __hip_bfloat16* hleaf = (__hip_bfloat16*)alloc((size_t)VV * DD * 2);
    __hip_bfloat16* cleaf = (__hip_bfloat16*)alloc((size_t)VV * DD * 2);
    float* Fh54 = (float*)alloc((size_t)VV * DD * 4);
    float* Gh = (float*)alloc((size_t)3 * VV * DD * 4);
    __hip_bfloat16* Tfc = (__hip_bfloat16*)alloc((size_t)VV * VV * DD * 2);
    (void)ws_size; (void)in_sizes; (void)n_in; (void)out_size;

    detect_idx64<<<1, 128, 0, stream>>>(edge_child, flag);
    prep_tables<<<54, 256, 0, stream>>>(W_if, b_f, W_i, b_i, W_o, b_o, W_u, b_u,
                                        wifc, tbi, tbo, tbu, hleaf, cleaf);
    prep_whf_bf<<<(DD * DD) / 256, 256, 0, stream>>>(W_hf, Whf_bf);
    prep_wg_bf<<<(3 * DD * DD) / 256, 256, 0, stream>>>(W_i, W_o, W_u, Wg_bf);
    {
        dim3 g(VV, 4);
        prep_typerows<<<g, 256, 0, stream>>>(hleaf, W_hf, W_i, W_o, W_u, Fh54, Gh);
    }
    prep_tfc<<<VV * VV, 256, 0, stream>>>(Fh54, wifc, cleaf, Tfc);

    // level 1: fully table-driven (both children are leaves)
    {
        int n = ls[2] - ls[1];  // 30000
        level1_kernel<<<(n * 64 + 255) / 256, 256, 0, stream>>>(
            node_types, edge_child, Gh, tbi, tbo, tbu, Tfc, Hint, Cint, flag, n);
    }

    // levels 2..9
    for (int l = 2; l < 10; l++) {
        int s = ls[l];
        int n = ls[l + 1] - s;
        int M2 = 2 * n;
        dim3 gf((M2 + 127) / 128, 4);
        gemm_f_mfma<<<gf, 256, 0, stream>>>(Hint, Cint, hleaf, cleaf, node_types, Whf_bf,
                                            edge_child, es[l], node_types + s, wifc, crem,
                                            flag, n);
        dim3 gg((n + 127) / 128, 4);
        gemm_g_mfma<<<gg, 512, 0, stream>>>(Hint, hleaf, node_types, Wg_bf,
                                            edge_child, es[l], node_types + s,
                                            tbi, tbo, tbu, crem,
                                            Hint + (size_t)(s - NLEAF) * DD,
                                            Cint + (size_t)(s - NLEAF) * DD,
                                            (l == 9) ? out : nullptr, flag, n);
    }
}

// Round 5
// 992.151 us; speedup vs baseline: 1.1660x; 1.1660x over previous
//
#include <hip/hip_runtime.h>
#include <hip/hip_bf16.h>

#define DD 512
#define VV 54
#define NLEAF 60000
#define NINT 59881   // 119881 - 60000 internal nodes

typedef __attribute__((ext_vector_type(8))) short bf16x8;
typedef __attribute__((ext_vector_type(4))) float f32x4;

// ---------- bf16 helpers ----------
__device__ __forceinline__ float bflo(unsigned int u) {
    union { unsigned int i; float f; } v; v.i = u << 16; return v.f;
}
__device__ __forceinline__ float bfhi(unsigned int u) {
    union { unsigned int i; float f; } v; v.i = u & 0xffff0000u; return v.f;
}
__device__ __forceinline__ float bfu2f(unsigned short u) {
    union { unsigned int i; float f; } v; v.i = ((unsigned int)u) << 16; return v.f;
}
__device__ __forceinline__ unsigned short f2bfu(float f) {
    union { unsigned int i; float f; } v; v.f = f;
    unsigned int x = v.i;
    unsigned int r = (x + 0x7FFFu + ((x >> 16) & 1u)) >> 16;  // RN-even
    return (unsigned short)r;
}
__device__ __forceinline__ unsigned int pack2(float lo, float hi) {
    return (unsigned int)f2bfu(lo) | ((unsigned int)f2bfu(hi) << 16);
}
__device__ __forceinline__ float b2f(__hip_bfloat16 x) { return __bfloat162float(x); }
__device__ __forceinline__ float sigm(float x) { return 1.f / (1.f + __expf(-x)); }

// ---------- edge-index dtype self-detection ----------
__global__ void detect_idx64(const int* __restrict__ ec, int* __restrict__ flag) {
    __shared__ int nz;
    if (threadIdx.x == 0) nz = 0;
    __syncthreads();
    if (ec[2 * threadIdx.x + 1] != 0) atomicAdd(&nz, 1);
    __syncthreads();
    if (threadIdx.x == 0) flag[0] = (nz == 0) ? 1 : 0;
}

// ---------- one-time prep ----------
__global__ void prep_tables(const float* __restrict__ W_if, const float* __restrict__ b_f,
                            const float* __restrict__ W_i, const float* __restrict__ b_i,
                            const float* __restrict__ W_o, const float* __restrict__ b_o,
                            const float* __restrict__ W_u, const float* __restrict__ b_u,
                            float* __restrict__ wifc, float* __restrict__ tbi,
                            float* __restrict__ tbo, float* __restrict__ tbu,
                            __hip_bfloat16* __restrict__ hleaf, __hip_bfloat16* __restrict__ cleaf) {
    int t = blockIdx.x;  // 0..53
    for (int d = threadIdx.x; d < DD; d += blockDim.x) {
        wifc[t * DD + d] = W_if[d * VV + t] + b_f[d];
        float vi = W_i[d * (VV + DD) + t] + b_i[d];
        float vo = W_o[d * (VV + DD) + t] + b_o[d];
        float vu = W_u[d * (VV + DD) + t] + b_u[d];
        tbi[t * DD + d] = vi; tbo[t * DD + d] = vo; tbu[t * DD + d] = vu;
        float gi = sigm(vi), go = sigm(vo), gu = tanhf(vu);
        float c = gi * gu;
        float h = go * tanhf(c);
        hleaf[t * DD + d] = __float2bfloat16(h);
        cleaf[t * DD + d] = __float2bfloat16(c);
    }
}

__global__ void prep_whf_bf(const float* __restrict__ W_hf, __hip_bfloat16* __restrict__ Whf_bf) {
    int idx = blockIdx.x * 256 + threadIdx.x;  // 512*512
    Whf_bf[idx] = __float2bfloat16(W_hf[idx]);
}

__global__ void prep_wg_bf(const float* __restrict__ W_i, const float* __restrict__ W_o,
                           const float* __restrict__ W_u, __hip_bfloat16* __restrict__ Wg_bf) {
    int idx = blockIdx.x * 256 + threadIdx.x;  // 3*512*512
    int m = idx >> 18;
    int rem = idx & (DD * DD - 1);
    int d = rem >> 9, k = rem & 511;
    const float* W = (m == 0) ? W_i : ((m == 1) ? W_o : W_u);
    Wg_bf[idx] = __float2bfloat16(W[d * (VV + DD) + VV + k]);
}

// Fh54[t][d] = hleaf[t] . W_hf[d][:]   (m=0)
// Gh[m-1][t][d] = hleaf[t] . W_m[d][VV:]  (m=1,2,3 -> i,o,u)
// wave-per-d, lanes split k (coalesced reads + shuffle reduce)
__global__ void prep_typerows(const __hip_bfloat16* __restrict__ hleaf,
                              const float* __restrict__ W_hf, const float* __restrict__ W_i,
                              const float* __restrict__ W_o, const float* __restrict__ W_u,
                              float* __restrict__ Fh54, float* __restrict__ Gh) {
    __shared__ float hsh[DD];
    int t = blockIdx.x, m = blockIdx.y;
    int lane = threadIdx.x & 63, w = threadIdx.x >> 6;
    for (int k = threadIdx.x; k < DD; k += 256) hsh[k] = b2f(hleaf[t * DD + k]);
    __syncthreads();
    const float* W; int stride, offc;
    if (m == 0) { W = W_hf; stride = DD; offc = 0; }
    else { W = (m == 1) ? W_i : ((m == 2) ? W_o : W_u); stride = VV + DD; offc = VV; }
    float* dst = (m == 0) ? (Fh54 + (size_t)t * DD) : (Gh + ((size_t)(m - 1) * VV + t) * DD);
    for (int d = w; d < DD; d += 4) {
        const float* wr = W + (size_t)d * stride + offc;
        float s = 0.f;
#pragma unroll
        for (int q = 0; q < 8; q++) s += wr[lane + 64 * q] * hsh[lane + 64 * q];
#pragma unroll
        for (int off = 32; off; off >>= 1) s += __shfl_down(s, off);
        if (lane == 0) dst[d] = s;
    }
}

// Tfc[tc][tp][d] = sigm(Fh54[tc][d] + wifc[tp][d]) * cleaf[tc][d]  (bf16)
__global__ void prep_tfc(const float* __restrict__ Fh54, const float* __restrict__ wifc,
                         const __hip_bfloat16* __restrict__ cleaf,
                         __hip_bfloat16* __restrict__ Tfc) {
    int pair = blockIdx.x;           // tc*54+tp, 2916 blocks
    int tc = pair / VV, tp = pair % VV;
    for (int d = threadIdx.x; d < DD; d += 256)
        Tfc[(size_t)pair * DD + d] = __float2bfloat16(
            sigm(Fh54[(size_t)tc * DD + d] + wifc[(size_t)tp * DD + d]) * b2f(cleaf[(size_t)tc * DD + d]));
}

// ---------- level-1 fused kernel: 128 threads/parent, all-vector coalesced reads ----------
__global__ __launch_bounds__(256) void level1_kernel(
    const int* __restrict__ nt, const int* __restrict__ ecb,
    const float* __restrict__ Gh, const float* __restrict__ tbi,
    const float* __restrict__ tbo, const float* __restrict__ tbu,
    const __hip_bfloat16* __restrict__ Tfc,
    __hip_bfloat16* __restrict__ Hrow, __hip_bfloat16* __restrict__ Crow,
    const int* __restrict__ idx64, int n) {
    int idx = blockIdx.x * 256 + threadIdx.x;
    int p = idx >> 7;
    if (p >= n) return;
    const int mode = idx64[0];
    int d0 = (idx & 127) << 2;
    int ta = nt[ecb[(2 * p) << mode]];
    int tb = nt[ecb[(2 * p + 1) << mode]];
    int tp = nt[NLEAF + p];
    ushort4 fa = *(const ushort4*)(Tfc + ((size_t)ta * VV + tp) * DD + d0);
    ushort4 fb = *(const ushort4*)(Tfc + ((size_t)tb * VV + tp) * DD + d0);
    float4 gia = *(const float4*)(Gh + (size_t)ta * DD + d0);
    float4 gib = *(const float4*)(Gh + (size_t)tb * DD + d0);
    float4 goa = *(const float4*)(Gh + (size_t)(VV + ta) * DD + d0);
    float4 gob = *(const float4*)(Gh + (size_t)(VV + tb) * DD + d0);
    float4 gua = *(const float4*)(Gh + (size_t)(2 * VV + ta) * DD + d0);
    float4 gub = *(const float4*)(Gh + (size_t)(2 * VV + tb) * DD + d0);
    float4 ti = *(const float4*)(tbi + (size_t)tp * DD + d0);
    float4 to = *(const float4*)(tbo + (size_t)tp * DD + d0);
    float4 tu = *(const float4*)(tbu + (size_t)tp * DD + d0);
    float cr[4] = {bfu2f(fa.x) + bfu2f(fb.x), bfu2f(fa.y) + bfu2f(fb.y),
                   bfu2f(fa.z) + bfu2f(fb.z), bfu2f(fa.w) + bfu2f(fb.w)};
    float ia[4] = {gia.x + gib.x + ti.x, gia.y + gib.y + ti.y,
                   gia.z + gib.z + ti.z, gia.w + gib.w + ti.w};
    float oa[4] = {goa.x + gob.x + to.x, goa.y + gob.y + to.y,
                   goa.z + gob.z + to.z, goa.w + gob.w + to.w};
    float ua[4] = {gua.x + gub.x + tu.x, gua.y + gub.y + tu.y,
                   gua.z + gub.z + tu.z, gua.w + gub.w + tu.w};
    float hv[4], cv[4];
#pragma unroll
    for (int j = 0; j < 4; j++) {
        float c = sigm(ia[j]) * tanhf(ua[j]) + cr[j];
        cv[j] = c;
        hv[j] = sigm(oa[j]) * tanhf(c);
    }
    ushort4 hp, cp;
    hp.x = f2bfu(hv[0]); hp.y = f2bfu(hv[1]); hp.z = f2bfu(hv[2]); hp.w = f2bfu(hv[3]);
    cp.x = f2bfu(cv[0]); cp.y = f2bfu(cv[1]); cp.z = f2bfu(cv[2]); cp.w = f2bfu(cv[3]);
    *(ushort4*)(Hrow + (size_t)p * DD + d0) = hp;
    *(ushort4*)(Crow + (size_t)p * DD + d0) = cp;
}

// ---------- gather helpers (leaves are virtual: table rows) ----------
__device__ __forceinline__ const __hip_bfloat16* h_row(int ci,
        const __hip_bfloat16* __restrict__ Hint, const __hip_bfloat16* __restrict__ hleaf,
        const int* __restrict__ nt) {
    return (ci < NLEAF) ? (hleaf + (size_t)nt[ci] * DD)
                        : (Hint + (size_t)(ci - NLEAF) * DD);
}
__device__ __forceinline__ const __hip_bfloat16* c_row(int ci,
        const __hip_bfloat16* __restrict__ Cint, const __hip_bfloat16* __restrict__ cleaf,
        const int* __restrict__ nt) {
    return (ci < NLEAF) ? (cleaf + (size_t)nt[ci] * DD)
                        : (Cint + (size_t)(ci - NLEAF) * DD);
}

// ============ GEMM F (MFMA): rows = edges, f-gate + in-lane pair-reduce -> crem ============
// tile 128(M) x 128(N), BK=32, 4 waves each 64x64. Fragment-major LDS (conflict-free).
__global__ __launch_bounds__(256) void gemm_f_mfma(
    const __hip_bfloat16* __restrict__ Hint, const __hip_bfloat16* __restrict__ Cint,
    const __hip_bfloat16* __restrict__ hleaf, const __hip_bfloat16* __restrict__ cleaf,
    const int* __restrict__ nt, const __hip_bfloat16* __restrict__ Whf_bf,
    const int* __restrict__ ecb, int eoff, const int* __restrict__ ntl,
    const float* __restrict__ wifc, __hip_bfloat16* __restrict__ crem,
    const int* __restrict__ idx64, int n) {
    __shared__ char lds[32768];  // 2 bufs x (A 8KB + B 8KB)
    const int M = 2 * n;
    const int mode = idx64[0];
    const int t = threadIdx.x;
    const int lane = t & 63, w = t >> 6, wr = w >> 1, wc = w & 1;
    const int row0 = blockIdx.x * 128, col0 = blockIdx.y * 128;

    const int srow = t & 127;
    const int sc = t >> 7;
    const __hip_bfloat16* aptr = nullptr;
    {
        int e = row0 + srow;
        if (e < M) {
            int ci = ecb[(eoff + e) << mode];
            aptr = h_row(ci, Hint, hleaf, nt);
        }
    }
    const __hip_bfloat16* bptr = Whf_bf + (size_t)(col0 + srow) * DD;
    const int wb = (srow >> 4) * 1024 + (srow & 15) * 16;

    f32x4 acc[4][4];
#pragma unroll
    for (int i = 0; i < 4; i++)
#pragma unroll
        for (int j = 0; j < 4; j++) acc[i][j] = {0.f, 0.f, 0.f, 0.f};

    uint4 ra0 = {0, 0, 0, 0}, ra1 = {0, 0, 0, 0}, rb0, rb1;
    if (aptr) { ra0 = *(const uint4*)(aptr + sc * 8); ra1 = *(const uint4*)(aptr + (sc + 2) * 8); }
    rb0 = *(const uint4*)(bptr + sc * 8);
    rb1 = *(const uint4*)(bptr + (sc + 2) * 8);

#pragma unroll 1
    for (int kt = 0; kt < 16; ++kt) {
        char* buf = lds + (kt & 1) * 16384;
        *(uint4*)(buf + wb + sc * 256) = ra0;
        *(uint4*)(buf + wb + (sc + 2) * 256) = ra1;
        *(uint4*)(buf + 8192 + wb + sc * 256) = rb0;
        *(uint4*)(buf + 8192 + wb + (sc + 2) * 256) = rb1;
        __syncthreads();
        if (kt < 15) {
            int ko = (kt + 1) * 32;
            if (aptr) {
                ra0 = *(const uint4*)(aptr + ko + sc * 8);
                ra1 = *(const uint4*)(aptr + ko + (sc + 2) * 8);
            }
            rb0 = *(const uint4*)(bptr + ko + sc * 8);
            rb1 = *(const uint4*)(bptr + ko + (sc + 2) * 8);
        }
        bf16x8 af[4], bfr[4];
#pragma unroll
        for (int i = 0; i < 4; i++)
            af[i] = *(const bf16x8*)(buf + (wr * 4 + i) * 1024 + lane * 16);
#pragma unroll
        for (int j = 0; j < 4; j++)
            bfr[j] = *(const bf16x8*)(buf + 8192 + (wc * 4 + j) * 1024 + lane * 16);
#pragma unroll
        for (int i = 0; i < 4; i++)
#pragma unroll
            for (int j = 0; j < 4; j++)
                acc[i][j] = __builtin_amdgcn_mfma_f32_16x16x32_bf16(af[i], bfr[j], acc[i][j], 0, 0, 0);
    }

    const int colb = col0 + wc * 64;
#pragma unroll
    for (int i = 0; i < 4; i++) {
        int er0 = row0 + wr * 64 + i * 16 + ((lane >> 4) << 2);
        if (er0 >= M) continue;
        bool hi = (er0 + 2) < M;
        int p0 = er0 >> 1;
        int t0 = ntl[p0];
        int t1 = hi ? ntl[p0 + 1] : 0;
        int ci0 = ecb[(eoff + er0) << mode];
        int ci1 = ecb[(eoff + er0 + 1) << mode];
        int ci2 = hi ? ecb[(eoff + er0 + 2) << mode] : ci0;
        int ci3 = hi ? ecb[(eoff + er0 + 3) << mode] : ci0;
        const __hip_bfloat16* cp0 = c_row(ci0, Cint, cleaf, nt);
        const __hip_bfloat16* cp1 = c_row(ci1, Cint, cleaf, nt);
        const __hip_bfloat16* cp2 = c_row(ci2, Cint, cleaf, nt);
        const __hip_bfloat16* cp3 = c_row(ci3, Cint, cleaf, nt);
        const float* wfa = wifc + (size_t)t0 * DD;
        const float* wfb = wifc + (size_t)t1 * DD;
#pragma unroll
        for (int j = 0; j < 4; j++) {
            int col = colb + j * 16 + (lane & 15);
            float wa = wfa[col], wbv = wfb[col];
            float s0 = sigm(acc[i][j].x + wa) * b2f(cp0[col])
                     + sigm(acc[i][j].y + wa) * b2f(cp1[col]);
            crem[(size_t)p0 * DD + col] = __float2bfloat16(s0);
            if (hi) {
                float s1 = sigm(acc[i][j].z + wbv) * b2f(cp2[col])
                         + sigm(acc[i][j].w + wbv) * b2f(cp3[col]);
                crem[(size_t)(p0 + 1) * DD + col] = __float2bfloat16(s1);
            }
        }
    }
}

// ============ GEMM G (MFMA): 256 threads, tile 64(M) x 128(N) x 3 gates, BK=32 ============
// single-buffered LDS (28KB) -> 4+ blocks/CU, 16 waves/CU. 4 waves each 32x64x3.
__global__ __launch_bounds__(256) void gemm_g_mfma(
    const __hip_bfloat16* __restrict__ Hint, const __hip_bfloat16* __restrict__ hleaf,
    const int* __restrict__ nt, const __hip_bfloat16* __restrict__ Wg_bf,
    const int* __restrict__ ecb, int eoff, const int* __restrict__ ntl,
    const float* __restrict__ tbi, const float* __restrict__ tbo,
    const float* __restrict__ tbu, const __hip_bfloat16* __restrict__ crem,
    __hip_bfloat16* __restrict__ Hrow, __hip_bfloat16* __restrict__ Crow,
    float* __restrict__ outF, const int* __restrict__ idx64, int n) {
    __shared__ char lds[28672];  // single buffer: A 4KB + B 24KB
    const int mode = idx64[0];
    const int t = threadIdx.x;
    const int lane = t & 63, w = t >> 6, wr = w >> 1, wc = w & 1;
    const int row0 = blockIdx.x * 64, col0 = blockIdx.y * 128;

    const int arow = t & 63, achk = t >> 6;
    const __hip_bfloat16 *pa = nullptr, *pb = nullptr;
    {
        int p = row0 + arow;
        if (p < n) {
            int c0 = ecb[(eoff + 2 * p) << mode];
            int c1 = ecb[(eoff + 2 * p + 1) << mode];
            pa = h_row(c0, Hint, hleaf, nt);
            pb = h_row(c1, Hint, hleaf, nt);
        }
    }
    const int wrA = (arow >> 4) * 1024 + (arow & 15) * 16 + achk * 256;
    const int bcol = t & 127, bcw = t >> 7;
    const __hip_bfloat16* bbase = Wg_bf + (size_t)(col0 + bcol) * DD;
    const int wrB = 4096 + (bcol >> 4) * 1024 + (bcol & 15) * 16;

    f32x4 acc[3][2][4];
#pragma unroll
    for (int m = 0; m < 3; m++)
#pragma unroll
        for (int i = 0; i < 2; i++)
#pragma unroll
            for (int j = 0; j < 4; j++) acc[m][i][j] = {0.f, 0.f, 0.f, 0.f};

    uint4 rax = {0, 0, 0, 0}, ray = {0, 0, 0, 0};
    uint4 rb[6];
    if (pa) { rax = *(const uint4*)(pa + achk * 8); ray = *(const uint4*)(pb + achk * 8); }
#pragma unroll
    for (int m = 0; m < 3; m++) {
        rb[2 * m] = *(const uint4*)(bbase + (size_t)m * DD * DD + bcw * 8);
        rb[2 * m + 1] = *(const uint4*)(bbase + (size_t)m * DD * DD + (bcw + 2) * 8);
    }

#pragma unroll 1
    for (int kt = 0; kt < 16; ++kt) {
        uint4 av;
        av.x = pack2(bflo(rax.x) + bflo(ray.x), bfhi(rax.x) + bfhi(ray.x));
        av.y = pack2(bflo(rax.y) + bflo(ray.y), bfhi(rax.y) + bfhi(ray.y));
        av.z = pack2(bflo(rax.z) + bflo(ray.z), bfhi(rax.z) + bfhi(ray.z));
        av.w = pack2(bflo(rax.w) + bflo(ray.w), bfhi(rax.w) + bfhi(ray.w));
        *(uint4*)(lds + wrA) = av;
#pragma unroll
        for (int m = 0; m < 3; m++) {
            *(uint4*)(lds + wrB + m * 8192 + bcw * 256) = rb[2 * m];
            *(uint4*)(lds + wrB + m * 8192 + (bcw + 2) * 256) = rb[2 * m + 1];
        }
        __syncthreads();
        if (kt < 15) {
            int ko = (kt + 1) * 32;
            if (pa) { rax = *(const uint4*)(pa + ko + achk * 8); ray = *(const uint4*)(pb + ko + achk * 8); }
#pragma unroll
            for (int m = 0; m < 3; m++) {
                rb[2 * m] = *(const uint4*)(bbase + (size_t)m * DD * DD + ko + bcw * 8);
                rb[2 * m + 1] = *(const uint4*)(bbase + (size_t)m * DD * DD + ko + (bcw + 2) * 8);
            }
        }
        bf16x8 af[2], bff[3][4];
#pragma unroll
        for (int i = 0; i < 2; i++)
            af[i] = *(const bf16x8*)(lds + (wr * 2 + i) * 1024 + lane * 16);
#pragma unroll
        for (int m = 0; m < 3; m++)
#pragma unroll
            for (int j = 0; j < 4; j++)
                bff[m][j] = *(const bf16x8*)(lds + 4096 + m * 8192 + (wc * 4 + j) * 1024 + lane * 16);
#pragma unroll
        for (int m = 0; m < 3; m++)
#pragma unroll
            for (int i = 0; i < 2; i++)
#pragma unroll
                for (int j = 0; j < 4; j++)
                    acc[m][i][j] = __builtin_amdgcn_mfma_f32_16x16x32_bf16(af[i], bff[m][j], acc[m][i][j], 0, 0, 0);
        __syncthreads();
    }

#pragma unroll
    for (int i = 0; i < 2; i++) {
        int r0 = row0 + wr * 32 + i * 16 + ((lane >> 4) << 2);
        int tt[4];
#pragma unroll
        for (int r = 0; r < 4; r++) tt[r] = (r0 + r < n) ? ntl[r0 + r] : 0;
#pragma unroll
        for (int j = 0; j < 4; j++) {
            int col = col0 + wc * 64 + j * 16 + (lane & 15);
#pragma unroll
            for (int r = 0; r < 4; r++) {
                int row = r0 + r;
                if (row >= n) continue;
                const float* pbi = tbi + (size_t)tt[r] * DD;
                const float* pbo = tbo + (size_t)tt[r] * DD;
                const float* pbu = tbu + (size_t)tt[r] * DD;
                float gi = sigm(acc[0][i][j][r] + pbi[col]);
                float go = sigm(acc[1][i][j][r] + pbo[col]);
                float gu = tanhf(acc[2][i][j][r] + pbu[col]);
                float c = gi * gu + b2f(crem[(size_t)row * DD + col]);
                float h = go * tanhf(c);
                Hrow[(size_t)row * DD + col] = __float2bfloat16(h);
                Crow[(size_t)row * DD + col] = __float2bfloat16(c);
                if (outF) outF[(size_t)row * DD + col] = h;
            }
        }
    }
}

extern "C" void kernel_launch(void* const* d_in, const int* in_sizes, int n_in,
                              void* d_out, int out_size, void* d_ws, size_t ws_size,
                              hipStream_t stream) {
    const int* node_types = (const int*)d_in[0];
    const int* edge_child = (const int*)d_in[2];
    const float* W_if = (const float*)d_in[6];
    const float* W_hf = (const float*)d_in[7];
    const float* b_f = (const float*)d_in[8];
    const float* W_i = (const float*)d_in[9];
    const float* b_i = (const float*)d_in[10];
    const float* W_o = (const float*)d_in[11];
    const float* b_o = (const float*)d_in[12];
    const float* W_u = (const float*)d_in[13];
    const float* b_u = (const float*)d_in[14];
    float* out = (float*)d_out;

    static const int ls[11] = {0, 60000, 90000, 105000, 112500, 116250,
                               118125, 119062, 119530, 119764, 119881};
    static const int es[11] = {0, 0, 60000, 90000, 105000, 112500,
                               116250, 118124, 119060, 119528, 119762};

    char* ws = (char*)d_ws;
    size_t off = 0;
    auto alloc = [&](size_t bytes) -> void* {
        void* p = ws + off;
        off += (bytes + 255) & ~(size_t)255;
        return p;
    };
    int* flag = (int*)alloc(256);
    __hip_bfloat16* Hint = (__hip_bfloat16*)alloc((size_t)NINT * DD * 2);
    __hip_bfloat16* Cint = (__hip_bfloat16*)alloc((size_t)NINT * DD * 2);
    __hip_bfloat16* crem = (__hip_bfloat16*)alloc((size_t)15000 * DD * 2);
    __hip_bfloat16* Whf_bf = (__hip_bfloat16*)alloc((size_t)DD * DD * 2);
    __hip_bfloat16* Wg_bf = (__hip_bfloat16*)alloc((size_t)3 * DD * DD * 2);
    float* wifc = (float*)alloc((size_t)VV * DD * 4);
    float* tbi = (float*)alloc((size_t)VV * DD * 4);
    float* tbo = (float*)alloc((size_t)VV * DD * 4);
    float* tbu = (float*)alloc((size_t)VV * DD * 4);
    __hip_bfloat16* hleaf = (__hip_bfloat16*)alloc((size_t)VV * DD * 2);
    __hip_bfloat16* cleaf = (__hip_bfloat16*)alloc((size_t)VV * DD * 2);
    float* Fh54 = (float*)alloc((size_t)VV * DD * 4);
    float* Gh = (float*)alloc((size_t)3 * VV * DD * 4);
    __hip_bfloat16* Tfc = (__hip_bfloat16*)alloc((size_t)VV * VV * DD * 2);
    (void)ws_size; (void)in_sizes; (void)n_in; (void)out_size;

    detect_idx64<<<1, 128, 0, stream>>>(edge_child, flag);
    prep_tables<<<54, 256, 0, stream>>>(W_if, b_f, W_i, b_i, W_o, b_o, W_u, b_u,
                                        wifc, tbi, tbo, tbu, hleaf, cleaf);
    prep_whf_bf<<<(DD * DD) / 256, 256, 0, stream>>>(W_hf, Whf_bf);
    prep_wg_bf<<<(3 * DD * DD) / 256, 256, 0, stream>>>(W_i, W_o, W_u, Wg_bf);
    {
        dim3 g(VV, 4);
        prep_typerows<<<g, 256, 0, stream>>>(hleaf, W_hf, W_i, W_o, W_u, Fh54, Gh);
    }
    prep_tfc<<<VV * VV, 256, 0, stream>>>(Fh54, wifc, cleaf, Tfc);

    // level 1: fully table-driven (both children are leaves)
    {
        int n = ls[2] - ls[1];  // 30000
        level1_kernel<<<(n * 128 + 255) / 256, 256, 0, stream>>>(
            node_types, edge_child, Gh, tbi, tbo, tbu, Tfc, Hint, Cint, flag, n);
    }

    // levels 2..9
    for (int l = 2; l < 10; l++) {
        int s = ls[l];
        int n = ls[l + 1] - s;
        int M2 = 2 * n;
        dim3 gf((M2 + 127) / 128, 4);
        gemm_f_mfma<<<gf, 256, 0, stream>>>(Hint, Cint, hleaf, cleaf, node_types, Whf_bf,
                                            edge_child, es[l], node_types + s, wifc, crem,
                                            flag, n);
        dim3 gg((n + 63) / 64, 4);
        gemm_g_mfma<<<gg, 256, 0, stream>>>(Hint, hleaf, node_types, Wg_bf,
                                            edge_child, es[l], node_types + s,
                                            tbi, tbo, tbu, crem,
                                            Hint + (size_t)(s - NLEAF) * DD,
                                            Cint + (size_t)(s - NLEAF) * DD,
                                            (l == 9) ? out : nullptr, flag, n);
    }
}